// Round 1
// 84.536 us; speedup vs baseline: 1.0021x; 1.0021x over previous
//
#include <hip/hip_runtime.h>
#include <math.h>

#define NW 4
#define NL 3

// ---------------------------------------------------------------------------
// Kernel 1 (one block, 256 threads): build the fixed 16x16 circuit unitary U,
// form C_j = sum_w W[j][w] * Re(U^dag D_w U), Pauli-contract to the 81x4
// multilinear coefficient tensor T. Bias folded into T[k=0].
//
// Restructured for latency: 12 threads compute the 12 Rot gate matrices in
// parallel (3 sincosf each, instead of 36 serial sincosf on all 256 threads);
// 16 threads then build U column-local in REGISTERS (gate application only
// mixes rows within a column; CNOT is a compile-time register permutation) —
// no barriers during the build. 3 __syncthreads total (was ~50).
// ---------------------------------------------------------------------------
__global__ void precompute_T(const float* __restrict__ params,  // (3,4,3)
                             const float* __restrict__ W,       // (4,4)
                             const float* __restrict__ bias,    // (4,)
                             float* __restrict__ ws)
{
    __shared__ float4 gm4[12][2];          // per gate: {m00,m01},{m10,m11} as (re,im) pairs
    __shared__ float Ure[16][16], Uim[16][16];
    __shared__ float C[4][16][16];
    const int tid = threadIdx.x;

    // Phase 0: gate matrices, one thread per (l,w) gate. Same formulas as before.
    if (tid < 12) {
        float phi = params[tid*3 + 0];
        float th  = params[tid*3 + 1];
        float om  = params[tid*3 + 2];
        float st, ct; sincosf(0.5f*th, &st, &ct);
        float sp, cp; sincosf(-0.5f*(phi+om), &sp, &cp); // e^{-i(phi+om)/2}
        float sm, cm; sincosf(-0.5f*(phi-om), &sm, &cm); // e^{-i(phi-om)/2}
        gm4[tid][0] = make_float4( cp*ct,  sp*ct, -cm*st,  sm*st); // m00re,m00im,m01re,m01im
        gm4[tid][1] = make_float4( cm*st,  sm*st,  cp*ct, -sp*ct); // m10re,m10im,m11re,m11im
    }
    __syncthreads();

    // Phase 1: 16 threads, each owns column `col` of U, all 16 rows in registers.
    if (tid < 16) {
        const int col = tid;
        float ur[16], ui[16];
        #pragma unroll
        for (int r = 0; r < 16; ++r) { ur[r] = (r == col) ? 1.f : 0.f; ui[r] = 0.f; }

        #pragma unroll
        for (int l = 0; l < NL; ++l) {
            #pragma unroll
            for (int w = 0; w < NW; ++w) {
                float4 g0 = gm4[l*4 + w][0];   // m00(re,im), m01(re,im)
                float4 g1 = gm4[l*4 + w][1];   // m10(re,im), m11(re,im)
                const int mask = 1 << (3 - w);
                #pragma unroll
                for (int s = 0; s < 16; ++s) {
                    if (s & mask) continue;    // compile-time after unroll
                    const int s1 = s | mask;
                    float u0r = ur[s],  u0i = ui[s];
                    float u1r = ur[s1], u1i = ui[s1];
                    // new[s0] = m00*u0 + m01*u1 ; new[s1] = m10*u0 + m11*u1
                    ur[s]  = (g0.x*u0r - g0.y*u0i) + (g0.z*u1r - g0.w*u1i);
                    ui[s]  = (g0.x*u0i + g0.y*u0r) + (g0.z*u1i + g0.w*u1r);
                    ur[s1] = (g1.x*u0r - g1.y*u0i) + (g1.z*u1r - g1.w*u1i);
                    ui[s1] = (g1.x*u0i + g1.y*u0r) + (g1.z*u1i + g1.w*u1r);
                }
            }
            // CNOT ring, range r: pure row permutation -> register swaps
            const int rr = (l % (NW-1)) + 1;
            #pragma unroll
            for (int w = 0; w < NW; ++w) {
                const int cmk = 1 << (3 - w);
                const int tmk = 1 << (3 - ((w + rr) % NW));
                #pragma unroll
                for (int s = 0; s < 16; ++s) {
                    if ((s & cmk) && !(s & tmk)) {
                        const int s1 = s | tmk;
                        float tr = ur[s], ti = ui[s];
                        ur[s] = ur[s1]; ui[s] = ui[s1];
                        ur[s1] = tr;    ui[s1] = ti;
                    }
                }
            }
        }
        #pragma unroll
        for (int r = 0; r < 16; ++r) { Ure[r][col] = ur[r]; Uim[r][col] = ui[r]; }
    }
    __syncthreads();

    // Phase 2: C_j[s][c] = sum_w W[j][w] * sum_r z_w(r) * Re(conj(U[r][s]) U[r][c])
    // pr computed once per r (was 4x); signs are compile-time after unroll.
    {
        const int s = tid >> 4, c = tid & 15;
        float A0 = 0.f, A1 = 0.f, A2 = 0.f, A3 = 0.f;
        #pragma unroll
        for (int r = 0; r < 16; ++r) {
            float pr = Ure[r][s]*Ure[r][c] + Uim[r][s]*Uim[r][c];
            A0 += (r & 8) ? -pr : pr;   // w=0 -> bit 3
            A1 += (r & 4) ? -pr : pr;   // w=1 -> bit 2
            A2 += (r & 2) ? -pr : pr;   // w=2 -> bit 1
            A3 += (r & 1) ? -pr : pr;   // w=3 -> bit 0
        }
        #pragma unroll
        for (int j = 0; j < 4; ++j) {
            float cj = W[j*4+0]*A0;
            cj += W[j*4+1]*A1;
            cj += W[j*4+2]*A2;
            cj += W[j*4+3]*A3;
            C[j][s][c] = cj;
        }
    }
    __syncthreads();

    // Phase 3: T[k][j] = (1/16) sum_{s,t} C_j[s,t] * prod_w sigma_{k_w}[s_w,t_w]
    if (tid < 81) {
        int k = tid;
        int kw[4] = { k/27, (k/9)%3, (k/3)%3, k%3 };
        int sb[4][2], tb[4][2]; float sg[4][2];
        for (int w = 0; w < 4; ++w) {
            int kk = kw[w];
            if (kk == 0)      { sb[w][0]=0; tb[w][0]=0; sg[w][0]= 1.f; sb[w][1]=1; tb[w][1]=1; sg[w][1]= 1.f; }
            else if (kk == 1) { sb[w][0]=0; tb[w][0]=0; sg[w][0]= 1.f; sb[w][1]=1; tb[w][1]=1; sg[w][1]=-1.f; }
            else              { sb[w][0]=0; tb[w][0]=1; sg[w][0]= 1.f; sb[w][1]=1; tb[w][1]=0; sg[w][1]= 1.f; }
        }
        float acc[4] = {0.f,0.f,0.f,0.f};
        for (int m = 0; m < 16; ++m) {
            int ss = 0, tt = 0; float sign = 1.f;
            for (int w = 0; w < 4; ++w) {
                int o = (m >> (3-w)) & 1;
                ss |= sb[w][o] << (3-w);
                tt |= tb[w][o] << (3-w);
                sign *= sg[w][o];
            }
            for (int j = 0; j < 4; ++j) acc[j] += sign * C[j][ss][tt];
        }
        for (int j = 0; j < 4; ++j) {
            float v = acc[j] * (1.f/16.f);
            if (k == 0) v += bias[j];     // fold bias into the constant term
            ws[k*4 + j] = v;
        }
    }
}

// ---------------------------------------------------------------------------
// Kernel 2: one thread = 4 patches (a 4x4 pixel block / 2x2 patch quad).
// Halves the per-patch LDS broadcast traffic vs 2-patch version; inner loop
// is 1 ds_read_b128 : 20 VALU -> VALU-bound. 64-thread blocks (3136 blocks)
// for better tail balance. Per-patch FMA order identical to previous kernel.
// ---------------------------------------------------------------------------
__device__ __forceinline__ void build9(float a0, float a1, float* p) {
    float c0, s0, c1, s1;
    __sincosf(a0, &s0, &c0);
    __sincosf(a1, &s1, &c1);
    p[0] = 1.f;  p[1] = c1;    p[2] = s1;
    p[3] = c0;   p[4] = c0*c1; p[5] = c0*s1;
    p[6] = s0;   p[7] = s0*c1; p[8] = s0*s1;
}

__global__ __launch_bounds__(64, 4) void quanv_main(const float* __restrict__ x,
                                                    const float* __restrict__ T,
                                                    float* __restrict__ out)
{
    __shared__ float4 sT[81];
    const int tid = threadIdx.x;
    sT[tid] = ((const float4*)T)[tid];
    if (tid < 17) sT[64 + tid] = ((const float4*)T)[64 + tid];
    __syncthreads();

    int t   = blockIdx.x * 64 + tid;       // 4096*7*7 = 200704 = 3136*64 exact
    int jt  = t % 7;                       // patch-col pair: cols 4jt..4jt+3
    int rem = t / 7;
    int i   = rem % 7;                     // patch-row pair: rows 4i..4i+3
    int b   = rem / 7;

    const float* base = x + b*784 + (4*i)*28 + 4*jt;
    float4 q0 = *(const float4*)(base);        // row 4i
    float4 q1 = *(const float4*)(base + 28);   // row 4i+1
    float4 q2 = *(const float4*)(base + 56);   // row 4i+2
    float4 q3 = *(const float4*)(base + 84);   // row 4i+3

    float pA01[9], pA23[9], pB01[9], pB23[9];
    float pC01[9], pC23[9], pD01[9], pD23[9];
    build9(q0.x, q0.y, pA01);  build9(q1.x, q1.y, pA23);   // TL patch (2i,   2jt  )
    build9(q0.z, q0.w, pB01);  build9(q1.z, q1.w, pB23);   // TR patch (2i,   2jt+1)
    build9(q2.x, q2.y, pC01);  build9(q3.x, q3.y, pC23);   // BL patch (2i+1, 2jt  )
    build9(q2.z, q2.w, pD01);  build9(q3.z, q3.w, pD23);   // BR patch (2i+1, 2jt+1)

    float oA0=0.f,oA1=0.f,oA2=0.f,oA3=0.f;
    float oB0=0.f,oB1=0.f,oB2=0.f,oB3=0.f;
    float oC0=0.f,oC1=0.f,oC2=0.f,oC3=0.f;
    float oD0=0.f,oD1=0.f,oD2=0.f,oD3=0.f;
    #pragma unroll
    for (int u = 0; u < 9; ++u) {
        float au = pA01[u], bu = pB01[u], cu = pC01[u], du = pD01[u];
        #pragma unroll
        for (int v = 0; v < 9; ++v) {
            float4 tv = sT[u*9 + v];           // wave-uniform LDS broadcast
            float qA = au * pA23[v];
            float qB = bu * pB23[v];
            float qC = cu * pC23[v];
            float qD = du * pD23[v];
            oA0 = fmaf(tv.x, qA, oA0);  oB0 = fmaf(tv.x, qB, oB0);
            oC0 = fmaf(tv.x, qC, oC0);  oD0 = fmaf(tv.x, qD, oD0);
            oA1 = fmaf(tv.y, qA, oA1);  oB1 = fmaf(tv.y, qB, oB1);
            oC1 = fmaf(tv.y, qC, oC1);  oD1 = fmaf(tv.y, qD, oD1);
            oA2 = fmaf(tv.z, qA, oA2);  oB2 = fmaf(tv.z, qB, oB2);
            oC2 = fmaf(tv.z, qC, oC2);  oD2 = fmaf(tv.z, qD, oD2);
            oA3 = fmaf(tv.w, qA, oA3);  oB3 = fmaf(tv.w, qB, oB3);
            oC3 = fmaf(tv.w, qC, oC3);  oD3 = fmaf(tv.w, qD, oD3);
        }
    }

    // patch index = b*196 + pi*14 + pj ; TL at (2i, 2jt)
    int p = b*196 + (2*i)*14 + 2*jt;
    float4* o = (float4*)out;
    o[p]      = make_float4(oA0, oA1, oA2, oA3);
    o[p + 1]  = make_float4(oB0, oB1, oB2, oB3);
    o[p + 14] = make_float4(oC0, oC1, oC2, oC3);
    o[p + 15] = make_float4(oD0, oD1, oD2, oD3);
}

extern "C" void kernel_launch(void* const* d_in, const int* in_sizes, int n_in,
                              void* d_out, int out_size, void* d_ws, size_t ws_size,
                              hipStream_t stream) {
    const float* x      = (const float*)d_in[0];   // (4096,1,28,28)
    const float* params = (const float*)d_in[1];   // (3,4,3)
    const float* W      = (const float*)d_in[2];   // (4,4)
    const float* bias   = (const float*)d_in[3];   // (4,)
    float* out = (float*)d_out;                    // (4096, 784)
    float* ws  = (float*)d_ws;                     // 324 floats used

    precompute_T<<<1, 256, 0, stream>>>(params, W, bias, ws);

    const int blocks = (4096 * 7 * 7) / 64;        // 3136, 4 patches per thread
    quanv_main<<<blocks, 64, 0, stream>>>(x, ws, out);
}